// Round 8
// baseline (177.321 us; speedup 1.0000x reference)
//
#include <hip/hip_runtime.h>

// All tensors float32. Output = concat(vec[3E], dist[E], switch[E], mask[E]).
//
// R1 post-mortem: 71us, HBM 20%, VALU 8% -> divergent-gather bound.
// R2: pack coords into float4[N] in d_ws -> single dwordx4 gather/node. 65us.
// R3/R4: nt loads streaming inputs + nt stores all outputs.
// R5 post-mortem: WRITE 107->75MB (nt vec-store amplification fixed, write
//   side now at ideal) but dur UNCHANGED 65us at 24% HBM, 9% VALU, 55% occ.
//   => NOT BW-bound. Latency-capacity bound on the 6.4M random 16B gathers:
//   always L1-miss (1.6MB table vs 32KB L1), throughput = per-CU outstanding
//   misses / L2-L3 latency. ~25K line-misses/CU * ~latency/MSHR ~= 65us.
// R6: 8 edges/thread (2x per-wave MLP: 16 gathers in flight, fewer total
//   instrs, same bytes). Discriminates wave-MLP-bound (dur -> ~45-50) vs
//   CU-MSHR-bound (dur flat ~65). Store policy kept from R5 (cached vec,
//   nt dist/sw/mask). Arithmetic unchanged (bit-exact: d<5 cliff; fp
//   contract OFF, numpy op order, OCML sqrtf).
// R7-R10: resubmits of R6 unchanged — R6-R9 all died in infra
//   (GPU acquisition timeout, pre-compile) with no counters; the
//   experiment has not yet run. Prediction stands. (Considered an
//   in-bench A/B bundle vs the measured R5 kernel; rejected — R5's 65us
//   is already well-measured, bundle would only double graded dur.)

typedef float f32x4 __attribute__((ext_vector_type(4)));
typedef int   i32x4 __attribute__((ext_vector_type(4)));

__device__ __forceinline__ void edge_math(
    float dx0, float dx1, float dx2,
    float sh0, float sh1, float sh2, const float c[9],
    float& v0, float& v1, float& v2, float& dist, float& sw, float& mk)
{
#pragma clang fp contract(off)
    float m0 = sh0 * c[0]; m0 = m0 + sh1 * c[3]; m0 = m0 + sh2 * c[6];
    float m1 = sh0 * c[1]; m1 = m1 + sh1 * c[4]; m1 = m1 + sh2 * c[7];
    float m2 = sh0 * c[2]; m2 = m2 + sh1 * c[5]; m2 = m2 + sh2 * c[8];
    v0 = dx0 + m0; v1 = dx1 + m1; v2 = dx2 + m2;
    float q = v0 * v0; q = q + v1 * v1; q = q + v2 * v2;
    dist = sqrtf(q);
    bool m = dist < 5.0f;
    float cv = cosf(dist * 0.62831853f);   // f32(pi/5)
    sw = m ? (0.5f * cv + 0.5f) : 0.0f;
    mk = m ? 1.0f : 0.0f;
}

// ---- prepass: coords[N,3] -> packed float4[N] in ws ----
__global__ __launch_bounds__(256) void pack_coords_kernel(
    const float* __restrict__ coords, float4* __restrict__ packed, int n_nodes)
{
    int i = blockIdx.x * blockDim.x + threadIdx.x;
    if (i >= n_nodes) return;
    const float* p = coords + 3 * (size_t)i;
    packed[i] = make_float4(p[0], p[1], p[2], 0.0f);
}

// ---- main kernel: 8 edges/thread, packed-float4 gathers ----
__global__ __launch_bounds__(256) void GraphProcessor_64012192579962_kernel(
    const float4* __restrict__ packed,  // [N] xyz_
    const int*   __restrict__ esrc,     // [E]
    const int*   __restrict__ edst,     // [E]
    const float* __restrict__ shifts,   // [E,3]
    const float* __restrict__ cells,    // [9]
    float* __restrict__ out_vec,        // [E,3]
    float* __restrict__ out_dist,       // [E]
    float* __restrict__ out_sw,         // [E]
    float* __restrict__ out_mask,       // [E]
    int n_octs, int n_edges)
{
#pragma clang fp contract(off)
    int t = blockIdx.x * blockDim.x + threadIdx.x;
    if (t >= n_octs) return;

    float c[9];
#pragma unroll
    for (int i = 0; i < 9; ++i) c[i] = cells[i];   // uniform -> scalar loads

    const int e0 = 8 * t;

    if (e0 + 7 < n_edges) {
        // streaming, read-once -> nontemporal (keep the coord table cached)
        i32x4 ss0 = __builtin_nontemporal_load((const i32x4*)esrc + 2 * t);
        i32x4 ss1 = __builtin_nontemporal_load((const i32x4*)esrc + 2 * t + 1);
        i32x4 dd0 = __builtin_nontemporal_load((const i32x4*)edst + 2 * t);
        i32x4 dd1 = __builtin_nontemporal_load((const i32x4*)edst + 2 * t + 1);
        const f32x4* shp = (const f32x4*)(shifts + 24 * (size_t)t);
        f32x4 h0 = __builtin_nontemporal_load(shp + 0);
        f32x4 h1 = __builtin_nontemporal_load(shp + 1);
        f32x4 h2 = __builtin_nontemporal_load(shp + 2);
        f32x4 h3 = __builtin_nontemporal_load(shp + 3);
        f32x4 h4 = __builtin_nontemporal_load(shp + 4);
        f32x4 h5 = __builtin_nontemporal_load(shp + 5);

        // issue all 16 gathers before any compute (max outstanding misses)
        float4 s0 = packed[ss0.x], s1 = packed[ss0.y], s2 = packed[ss0.z], s3 = packed[ss0.w];
        float4 s4 = packed[ss1.x], s5 = packed[ss1.y], s6 = packed[ss1.z], s7 = packed[ss1.w];
        float4 d0 = packed[dd0.x], d1 = packed[dd0.y], d2 = packed[dd0.z], d3 = packed[dd0.w];
        float4 d4 = packed[dd1.x], d5 = packed[dd1.y], d6 = packed[dd1.z], d7 = packed[dd1.w];

        float v[24], di[8], sw[8], mk[8];
        edge_math(d0.x - s0.x, d0.y - s0.y, d0.z - s0.z, h0.x, h0.y, h0.z, c, v[0],  v[1],  v[2],  di[0], sw[0], mk[0]);
        edge_math(d1.x - s1.x, d1.y - s1.y, d1.z - s1.z, h0.w, h1.x, h1.y, c, v[3],  v[4],  v[5],  di[1], sw[1], mk[1]);
        edge_math(d2.x - s2.x, d2.y - s2.y, d2.z - s2.z, h1.z, h1.w, h2.x, c, v[6],  v[7],  v[8],  di[2], sw[2], mk[2]);
        edge_math(d3.x - s3.x, d3.y - s3.y, d3.z - s3.z, h2.y, h2.z, h2.w, c, v[9],  v[10], v[11], di[3], sw[3], mk[3]);
        edge_math(d4.x - s4.x, d4.y - s4.y, d4.z - s4.z, h3.x, h3.y, h3.z, c, v[12], v[13], v[14], di[4], sw[4], mk[4]);
        edge_math(d5.x - s5.x, d5.y - s5.y, d5.z - s5.z, h3.w, h4.x, h4.y, c, v[15], v[16], v[17], di[5], sw[5], mk[5]);
        edge_math(d6.x - s6.x, d6.y - s6.y, d6.z - s6.z, h4.z, h4.w, h5.x, c, v[18], v[19], v[20], di[6], sw[6], mk[6]);
        edge_math(d7.x - s7.x, d7.y - s7.y, d7.z - s7.z, h5.y, h5.z, h5.w, c, v[21], v[22], v[23], di[7], sw[7], mk[7]);

        // vec: CACHED stores (L2 merges the stride pattern into full lines;
        // nt here caused 1.4x write amplification -- R5 post-mortem).
        float4* ov = (float4*)(out_vec + 24 * (size_t)t);
        ov[0] = make_float4(v[0],  v[1],  v[2],  v[3]);
        ov[1] = make_float4(v[4],  v[5],  v[6],  v[7]);
        ov[2] = make_float4(v[8],  v[9],  v[10], v[11]);
        ov[3] = make_float4(v[12], v[13], v[14], v[15]);
        ov[4] = make_float4(v[16], v[17], v[18], v[19]);
        ov[5] = make_float4(v[20], v[21], v[22], v[23]);

        // dist/sw/mask: lane-contiguous full lines -> keep nt.
        f32x4 od0 = { di[0], di[1], di[2], di[3] }, od1 = { di[4], di[5], di[6], di[7] };
        f32x4 os0 = { sw[0], sw[1], sw[2], sw[3] }, os1 = { sw[4], sw[5], sw[6], sw[7] };
        f32x4 om0 = { mk[0], mk[1], mk[2], mk[3] }, om1 = { mk[4], mk[5], mk[6], mk[7] };
        __builtin_nontemporal_store(od0, (f32x4*)out_dist + 2 * t);
        __builtin_nontemporal_store(od1, (f32x4*)out_dist + 2 * t + 1);
        __builtin_nontemporal_store(os0, (f32x4*)out_sw   + 2 * t);
        __builtin_nontemporal_store(os1, (f32x4*)out_sw   + 2 * t + 1);
        __builtin_nontemporal_store(om0, (f32x4*)out_mask + 2 * t);
        __builtin_nontemporal_store(om1, (f32x4*)out_mask + 2 * t + 1);
    } else {
        for (int e = e0; e < n_edges; ++e) {
            float4 s = packed[esrc[e]], d = packed[edst[e]];
            float v0, v1, v2, di, sw, mk;
            edge_math(d.x - s.x, d.y - s.y, d.z - s.z,
                      shifts[3 * (size_t)e], shifts[3 * (size_t)e + 1],
                      shifts[3 * (size_t)e + 2], c, v0, v1, v2, di, sw, mk);
            out_vec[3 * (size_t)e]     = v0;
            out_vec[3 * (size_t)e + 1] = v1;
            out_vec[3 * (size_t)e + 2] = v2;
            out_dist[e] = di;
            out_sw[e]   = sw;
            out_mask[e] = mk;
        }
    }
}

// ---- fallback (ws too small): 12B struct gathers straight from coords ----
struct F3 { float x, y, z; };

__global__ __launch_bounds__(256) void GraphProcessor_fallback_kernel(
    const float* __restrict__ coords,
    const int*   __restrict__ esrc,
    const int*   __restrict__ edst,
    const float* __restrict__ shifts,
    const float* __restrict__ cells,
    float* __restrict__ out_vec,
    float* __restrict__ out_dist,
    float* __restrict__ out_sw,
    float* __restrict__ out_mask,
    int n_quads, int n_edges)
{
#pragma clang fp contract(off)
    int t = blockIdx.x * blockDim.x + threadIdx.x;
    if (t >= n_quads) return;

    float c[9];
#pragma unroll
    for (int i = 0; i < 9; ++i) c[i] = cells[i];

    const F3* nodes = (const F3*)coords;
    const int e0 = 4 * t;

    if (e0 + 3 < n_edges) {
        i32x4 ss = __builtin_nontemporal_load((const i32x4*)esrc + t);
        i32x4 dd = __builtin_nontemporal_load((const i32x4*)edst + t);
        const f32x4* shp = (const f32x4*)(shifts + 12 * (size_t)t);
        f32x4 h0 = __builtin_nontemporal_load(shp + 0);
        f32x4 h1 = __builtin_nontemporal_load(shp + 1);
        f32x4 h2 = __builtin_nontemporal_load(shp + 2);

        F3 s0 = nodes[ss.x], s1 = nodes[ss.y], s2 = nodes[ss.z], s3 = nodes[ss.w];
        F3 d0 = nodes[dd.x], d1 = nodes[dd.y], d2 = nodes[dd.z], d3 = nodes[dd.w];

        float v[12], di[4], sw[4], mk[4];
        edge_math(d0.x - s0.x, d0.y - s0.y, d0.z - s0.z, h0.x, h0.y, h0.z, c, v[0], v[1],  v[2],  di[0], sw[0], mk[0]);
        edge_math(d1.x - s1.x, d1.y - s1.y, d1.z - s1.z, h0.w, h1.x, h1.y, c, v[3], v[4],  v[5],  di[1], sw[1], mk[1]);
        edge_math(d2.x - s2.x, d2.y - s2.y, d2.z - s2.z, h1.z, h1.w, h2.x, c, v[6], v[7],  v[8],  di[2], sw[2], mk[2]);
        edge_math(d3.x - s3.x, d3.y - s3.y, d3.z - s3.z, h2.y, h2.z, h2.w, c, v[9], v[10], v[11], di[3], sw[3], mk[3]);

        float4* ov = (float4*)(out_vec + 12 * (size_t)t);
        ov[0] = make_float4(v[0], v[1], v[2],  v[3]);
        ov[1] = make_float4(v[4], v[5], v[6],  v[7]);
        ov[2] = make_float4(v[8], v[9], v[10], v[11]);

        f32x4 od = { di[0], di[1], di[2], di[3] };
        f32x4 os = { sw[0], sw[1], sw[2], sw[3] };
        f32x4 om = { mk[0], mk[1], mk[2], mk[3] };
        __builtin_nontemporal_store(od, (f32x4*)out_dist + t);
        __builtin_nontemporal_store(os, (f32x4*)out_sw   + t);
        __builtin_nontemporal_store(om, (f32x4*)out_mask + t);
    } else {
        for (int e = e0; e < n_edges; ++e) {
            F3 s = nodes[esrc[e]], d = nodes[edst[e]];
            float v0, v1, v2, di, sw, mk;
            edge_math(d.x - s.x, d.y - s.y, d.z - s.z,
                      shifts[3 * (size_t)e], shifts[3 * (size_t)e + 1],
                      shifts[3 * (size_t)e + 2], c, v0, v1, v2, di, sw, mk);
            out_vec[3 * (size_t)e]     = v0;
            out_vec[3 * (size_t)e + 1] = v1;
            out_vec[3 * (size_t)e + 2] = v2;
            out_dist[e] = di;
            out_sw[e]   = sw;
            out_mask[e] = mk;
        }
    }
}

extern "C" void kernel_launch(void* const* d_in, const int* in_sizes, int n_in,
                              void* d_out, int out_size, void* d_ws, size_t ws_size,
                              hipStream_t stream) {
    const float* coords = (const float*)d_in[0];
    const int*   esrc   = (const int*)d_in[1];
    const int*   edst   = (const int*)d_in[2];
    const float* shifts = (const float*)d_in[3];
    const float* cells  = (const float*)d_in[4];

    const int N = in_sizes[0] / 3;  // n_nodes
    const int E = in_sizes[1];      // n_edges

    float* out      = (float*)d_out;
    float* out_vec  = out;                     // [E,3]
    float* out_dist = out + 3 * (size_t)E;     // [E]
    float* out_sw   = out_dist + E;            // [E]
    float* out_mask = out_sw + E;              // [E]

    if (ws_size >= (size_t)N * sizeof(float4)) {
        const int n_octs = (E + 7) / 8;
        float4* packed = (float4*)d_ws;
        pack_coords_kernel<<<(N + 255) / 256, 256, 0, stream>>>(coords, packed, N);
        GraphProcessor_64012192579962_kernel<<<(n_octs + 255) / 256, 256, 0, stream>>>(
            packed, esrc, edst, shifts, cells,
            out_vec, out_dist, out_sw, out_mask, n_octs, E);
    } else {
        const int n_quads = (E + 3) / 4;
        GraphProcessor_fallback_kernel<<<(n_quads + 255) / 256, 256, 0, stream>>>(
            coords, esrc, edst, shifts, cells,
            out_vec, out_dist, out_sw, out_mask, n_quads, E);
    }
}

// Round 9
// 172.591 us; speedup vs baseline: 1.0274x; 1.0274x over previous
//
#include <hip/hip_runtime.h>

// All tensors float32. Output = concat(vec[3E], dist[E], switch[E], mask[E]).
//
// R1: 71us, HBM 20%, VALU 8% -> divergent-gather bound.
// R2: pack coords into float4[N] in d_ws -> single dwordx4 gather/node. 65us.
// R3/R4: nt loads streaming inputs + nt stores all outputs.
// R5 post-mortem: WRITE 107->75MB (nt vec-store amplification fixed) but dur
//   UNCHANGED 65us at 24% HBM, 9% VALU, 55% occ => not BW-bound.
// R6 post-mortem (8 edges/thread): dur 72us REGRESSION, occ 55->29%, VGPR 60,
//   bytes at ideal (43.5/76MB). Total outstanding gathers ~constant across
//   R5/R6 (141 vs 149) yet dur tracked RESIDENT WAVES, not per-wave MLP.
//   => limiter is wave-count latency-hiding/issue, NOT a per-CU miss pool.
//   Fatter threads are the wrong direction.
// R11: 2 edges/thread (3rd point on batching curve: 8->72, 4->65, 2->?).
//   2x waves (~25K), VGPR <=32, same bytes, same nt policy as R5 (nt
//   streaming loads; cached strided vec stores; nt contiguous dist/sw/mask
//   stores - still lane-contiguous as dwordx2). Predict dur 55-60 if
//   wave-count-bound, flat 63-67 if L2 random-request wall (-> then sc0
//   L1-bypass gathers or roofline). Arithmetic unchanged (bit-exact: d<5
//   cliff; fp contract OFF, numpy op order, OCML sqrtf).

typedef float f32x4 __attribute__((ext_vector_type(4)));
typedef float f32x2 __attribute__((ext_vector_type(2)));
typedef int   i32x4 __attribute__((ext_vector_type(4)));
typedef int   i32x2 __attribute__((ext_vector_type(2)));

__device__ __forceinline__ void edge_math(
    float dx0, float dx1, float dx2,
    float sh0, float sh1, float sh2, const float c[9],
    float& v0, float& v1, float& v2, float& dist, float& sw, float& mk)
{
#pragma clang fp contract(off)
    float m0 = sh0 * c[0]; m0 = m0 + sh1 * c[3]; m0 = m0 + sh2 * c[6];
    float m1 = sh0 * c[1]; m1 = m1 + sh1 * c[4]; m1 = m1 + sh2 * c[7];
    float m2 = sh0 * c[2]; m2 = m2 + sh1 * c[5]; m2 = m2 + sh2 * c[8];
    v0 = dx0 + m0; v1 = dx1 + m1; v2 = dx2 + m2;
    float q = v0 * v0; q = q + v1 * v1; q = q + v2 * v2;
    dist = sqrtf(q);
    bool m = dist < 5.0f;
    float cv = cosf(dist * 0.62831853f);   // f32(pi/5)
    sw = m ? (0.5f * cv + 0.5f) : 0.0f;
    mk = m ? 1.0f : 0.0f;
}

// ---- prepass: coords[N,3] -> packed float4[N] in ws ----
__global__ __launch_bounds__(256) void pack_coords_kernel(
    const float* __restrict__ coords, float4* __restrict__ packed, int n_nodes)
{
    int i = blockIdx.x * blockDim.x + threadIdx.x;
    if (i >= n_nodes) return;
    const float* p = coords + 3 * (size_t)i;
    packed[i] = make_float4(p[0], p[1], p[2], 0.0f);
}

// ---- main kernel: 2 edges/thread, packed-float4 gathers ----
__global__ __launch_bounds__(256) void GraphProcessor_64012192579962_kernel(
    const float4* __restrict__ packed,  // [N] xyz_
    const int*   __restrict__ esrc,     // [E]
    const int*   __restrict__ edst,     // [E]
    const float* __restrict__ shifts,   // [E,3]
    const float* __restrict__ cells,    // [9]
    float* __restrict__ out_vec,        // [E,3]
    float* __restrict__ out_dist,       // [E]
    float* __restrict__ out_sw,         // [E]
    float* __restrict__ out_mask,       // [E]
    int n_pairs, int n_edges)
{
#pragma clang fp contract(off)
    int t = blockIdx.x * blockDim.x + threadIdx.x;
    if (t >= n_pairs) return;

    float c[9];
#pragma unroll
    for (int i = 0; i < 9; ++i) c[i] = cells[i];   // uniform -> scalar loads

    const int e0 = 2 * t;

    if (e0 + 1 < n_edges) {
        // streaming, read-once -> nontemporal (keep the coord table cached)
        i32x2 ss = __builtin_nontemporal_load((const i32x2*)esrc + t);
        i32x2 dd = __builtin_nontemporal_load((const i32x2*)edst + t);
        const f32x2* shp = (const f32x2*)(shifts + 6 * (size_t)t);
        f32x2 ha = __builtin_nontemporal_load(shp + 0);   // e0: sh0, sh1
        f32x2 hb = __builtin_nontemporal_load(shp + 1);   // e0: sh2 | e1: sh0
        f32x2 hc = __builtin_nontemporal_load(shp + 2);   // e1: sh1, sh2

        // issue all 4 gathers before any compute
        float4 s0 = packed[ss.x], s1 = packed[ss.y];
        float4 d0 = packed[dd.x], d1 = packed[dd.y];

        float v[6], di[2], sw[2], mk[2];
        edge_math(d0.x - s0.x, d0.y - s0.y, d0.z - s0.z, ha.x, ha.y, hb.x, c, v[0], v[1], v[2], di[0], sw[0], mk[0]);
        edge_math(d1.x - s1.x, d1.y - s1.y, d1.z - s1.z, hb.y, hc.x, hc.y, c, v[3], v[4], v[5], di[1], sw[1], mk[1]);

        // vec: CACHED stores (L2 merges the stride pattern into full lines;
        // nt on strided vec stores caused 1.4x write amplification -- R5).
        f32x2* ov = (f32x2*)(out_vec + 6 * (size_t)t);
        f32x2 o0 = { v[0], v[1] };
        f32x2 o1 = { v[2], v[3] };
        f32x2 o2 = { v[4], v[5] };
        ov[0] = o0; ov[1] = o1; ov[2] = o2;

        // dist/sw/mask: lane-contiguous full lines -> keep nt.
        f32x2 od = { di[0], di[1] };
        f32x2 os = { sw[0], sw[1] };
        f32x2 om = { mk[0], mk[1] };
        __builtin_nontemporal_store(od, (f32x2*)out_dist + t);
        __builtin_nontemporal_store(os, (f32x2*)out_sw   + t);
        __builtin_nontemporal_store(om, (f32x2*)out_mask + t);
    } else {
        for (int e = e0; e < n_edges; ++e) {
            float4 s = packed[esrc[e]], d = packed[edst[e]];
            float v0, v1, v2, di, sw, mk;
            edge_math(d.x - s.x, d.y - s.y, d.z - s.z,
                      shifts[3 * (size_t)e], shifts[3 * (size_t)e + 1],
                      shifts[3 * (size_t)e + 2], c, v0, v1, v2, di, sw, mk);
            out_vec[3 * (size_t)e]     = v0;
            out_vec[3 * (size_t)e + 1] = v1;
            out_vec[3 * (size_t)e + 2] = v2;
            out_dist[e] = di;
            out_sw[e]   = sw;
            out_mask[e] = mk;
        }
    }
}

// ---- fallback (ws too small): 12B struct gathers straight from coords ----
struct F3 { float x, y, z; };

__global__ __launch_bounds__(256) void GraphProcessor_fallback_kernel(
    const float* __restrict__ coords,
    const int*   __restrict__ esrc,
    const int*   __restrict__ edst,
    const float* __restrict__ shifts,
    const float* __restrict__ cells,
    float* __restrict__ out_vec,
    float* __restrict__ out_dist,
    float* __restrict__ out_sw,
    float* __restrict__ out_mask,
    int n_quads, int n_edges)
{
#pragma clang fp contract(off)
    int t = blockIdx.x * blockDim.x + threadIdx.x;
    if (t >= n_quads) return;

    float c[9];
#pragma unroll
    for (int i = 0; i < 9; ++i) c[i] = cells[i];

    const F3* nodes = (const F3*)coords;
    const int e0 = 4 * t;

    if (e0 + 3 < n_edges) {
        i32x4 ss = __builtin_nontemporal_load((const i32x4*)esrc + t);
        i32x4 dd = __builtin_nontemporal_load((const i32x4*)edst + t);
        const f32x4* shp = (const f32x4*)(shifts + 12 * (size_t)t);
        f32x4 h0 = __builtin_nontemporal_load(shp + 0);
        f32x4 h1 = __builtin_nontemporal_load(shp + 1);
        f32x4 h2 = __builtin_nontemporal_load(shp + 2);

        F3 s0 = nodes[ss.x], s1 = nodes[ss.y], s2 = nodes[ss.z], s3 = nodes[ss.w];
        F3 d0 = nodes[dd.x], d1 = nodes[dd.y], d2 = nodes[dd.z], d3 = nodes[dd.w];

        float v[12], di[4], sw[4], mk[4];
        edge_math(d0.x - s0.x, d0.y - s0.y, d0.z - s0.z, h0.x, h0.y, h0.z, c, v[0], v[1],  v[2],  di[0], sw[0], mk[0]);
        edge_math(d1.x - s1.x, d1.y - s1.y, d1.z - s1.z, h0.w, h1.x, h1.y, c, v[3], v[4],  v[5],  di[1], sw[1], mk[1]);
        edge_math(d2.x - s2.x, d2.y - s2.y, d2.z - s2.z, h1.z, h1.w, h2.x, c, v[6], v[7],  v[8],  di[2], sw[2], mk[2]);
        edge_math(d3.x - s3.x, d3.y - s3.y, d3.z - s3.z, h2.y, h2.z, h2.w, c, v[9], v[10], v[11], di[3], sw[3], mk[3]);

        float4* ov = (float4*)(out_vec + 12 * (size_t)t);
        ov[0] = make_float4(v[0], v[1], v[2],  v[3]);
        ov[1] = make_float4(v[4], v[5], v[6],  v[7]);
        ov[2] = make_float4(v[8], v[9], v[10], v[11]);

        f32x4 od = { di[0], di[1], di[2], di[3] };
        f32x4 os = { sw[0], sw[1], sw[2], sw[3] };
        f32x4 om = { mk[0], mk[1], mk[2], mk[3] };
        __builtin_nontemporal_store(od, (f32x4*)out_dist + t);
        __builtin_nontemporal_store(os, (f32x4*)out_sw   + t);
        __builtin_nontemporal_store(om, (f32x4*)out_mask + t);
    } else {
        for (int e = e0; e < n_edges; ++e) {
            F3 s = nodes[esrc[e]], d = nodes[edst[e]];
            float v0, v1, v2, di, sw, mk;
            edge_math(d.x - s.x, d.y - s.y, d.z - s.z,
                      shifts[3 * (size_t)e], shifts[3 * (size_t)e + 1],
                      shifts[3 * (size_t)e + 2], c, v0, v1, v2, di, sw, mk);
            out_vec[3 * (size_t)e]     = v0;
            out_vec[3 * (size_t)e + 1] = v1;
            out_vec[3 * (size_t)e + 2] = v2;
            out_dist[e] = di;
            out_sw[e]   = sw;
            out_mask[e] = mk;
        }
    }
}

extern "C" void kernel_launch(void* const* d_in, const int* in_sizes, int n_in,
                              void* d_out, int out_size, void* d_ws, size_t ws_size,
                              hipStream_t stream) {
    const float* coords = (const float*)d_in[0];
    const int*   esrc   = (const int*)d_in[1];
    const int*   edst   = (const int*)d_in[2];
    const float* shifts = (const float*)d_in[3];
    const float* cells  = (const float*)d_in[4];

    const int N = in_sizes[0] / 3;  // n_nodes
    const int E = in_sizes[1];      // n_edges

    float* out      = (float*)d_out;
    float* out_vec  = out;                     // [E,3]
    float* out_dist = out + 3 * (size_t)E;     // [E]
    float* out_sw   = out_dist + E;            // [E]
    float* out_mask = out_sw + E;              // [E]

    if (ws_size >= (size_t)N * sizeof(float4)) {
        const int n_pairs = (E + 1) / 2;
        float4* packed = (float4*)d_ws;
        pack_coords_kernel<<<(N + 255) / 256, 256, 0, stream>>>(coords, packed, N);
        GraphProcessor_64012192579962_kernel<<<(n_pairs + 255) / 256, 256, 0, stream>>>(
            packed, esrc, edst, shifts, cells,
            out_vec, out_dist, out_sw, out_mask, n_pairs, E);
    } else {
        const int n_quads = (E + 3) / 4;
        GraphProcessor_fallback_kernel<<<(n_quads + 255) / 256, 256, 0, stream>>>(
            coords, esrc, edst, shifts, cells,
            out_vec, out_dist, out_sw, out_mask, n_quads, E);
    }
}

// Round 10
// 165.374 us; speedup vs baseline: 1.0722x; 1.0436x over previous
//
#include <hip/hip_runtime.h>

// All tensors float32. Output = concat(vec[3E], dist[E], switch[E], mask[E]).
//
// R2: packed float4[N] table in d_ws -> 1 dwordx4 gather/node. 65us.
// R5: nt streaming loads; cached vec stores (nt+stride48 amplified 1.4x);
//   nt contiguous dist/sw/mask. WRITE 107->75MB ideal, dur flat 65us.
// R6: 8 edges/thread -> 72us REGRESSION (occ 29%). R11: 2 edges/thread ->
//   65.9us flat (occ 66%). Batching curve 8/4/2 = 72/65/66: dur invariant
//   to wave count AND per-wave MLP => saturated FIXED-RATE resource.
//   Arithmetic: 6.4M random gathers x 64B line = 410MB / 65us = 6.3 TB/s
//   of random cache-line service — at the L2/L3 random-access wall.
// R12 (this): last untested lever — the 38MB cached (write-allocate)
//   out_vec stores churn L2 and evict the 1.6MB coord table, pushing
//   gathers from L2-hit (~200cy) to L3 (~400-600cy) service. Fix: per-wave
//   LDS transpose of vec (64x20-float padded rows, 2-way banks = free) so
//   vec stores become lane-contiguous nt dwordx4 -> ALL outputs bypass L2
//   allocation; only gathers allocate. Wave-private LDS, no barrier
//   (wave-synchronous ds_write->ds_read, lgkmcnt-ordered). Pure data
//   movement — bit-exact (d<5 cliff; fp contract OFF, numpy op order).
//   Predict: WRITE ~75MB, FETCH ~47MB; dur 55-60 if L2-churn theory right,
//   flat 64-67 => request-rate wall confirmed -> ROOFLINE next round.

typedef float f32x4 __attribute__((ext_vector_type(4)));
typedef int   i32x4 __attribute__((ext_vector_type(4)));

__device__ __forceinline__ void edge_math(
    float dx0, float dx1, float dx2,
    float sh0, float sh1, float sh2, const float c[9],
    float& v0, float& v1, float& v2, float& dist, float& sw, float& mk)
{
#pragma clang fp contract(off)
    float m0 = sh0 * c[0]; m0 = m0 + sh1 * c[3]; m0 = m0 + sh2 * c[6];
    float m1 = sh0 * c[1]; m1 = m1 + sh1 * c[4]; m1 = m1 + sh2 * c[7];
    float m2 = sh0 * c[2]; m2 = m2 + sh1 * c[5]; m2 = m2 + sh2 * c[8];
    v0 = dx0 + m0; v1 = dx1 + m1; v2 = dx2 + m2;
    float q = v0 * v0; q = q + v1 * v1; q = q + v2 * v2;
    dist = sqrtf(q);
    bool m = dist < 5.0f;
    float cv = cosf(dist * 0.62831853f);   // f32(pi/5)
    sw = m ? (0.5f * cv + 0.5f) : 0.0f;
    mk = m ? 1.0f : 0.0f;
}

// ---- prepass: coords[N,3] -> packed float4[N] in ws ----
// cached stores: the table is the one thing we WANT resident in L2/L3.
__global__ __launch_bounds__(256) void pack_coords_kernel(
    const float* __restrict__ coords, float4* __restrict__ packed, int n_nodes)
{
    int i = blockIdx.x * blockDim.x + threadIdx.x;
    if (i >= n_nodes) return;
    const float* p = coords + 3 * (size_t)i;
    packed[i] = make_float4(p[0], p[1], p[2], 0.0f);
}

// ---- main kernel: 4 edges/thread, LDS-transposed nt vec stores ----
__global__ __launch_bounds__(256) void GraphProcessor_64012192579962_kernel(
    const float4* __restrict__ packed,  // [N] xyz_
    const int*   __restrict__ esrc,     // [E]
    const int*   __restrict__ edst,     // [E]
    const float* __restrict__ shifts,   // [E,3]
    const float* __restrict__ cells,    // [9]
    float* __restrict__ out_vec,        // [E,3]
    float* __restrict__ out_dist,       // [E]
    float* __restrict__ out_sw,         // [E]
    float* __restrict__ out_mask,       // [E]
    int n_quads, int n_edges)
{
#pragma clang fp contract(off)
    // per-wave transpose buffer: 64 rows x 20 floats (pad 12->20: 16B-aligned
    // rows, 80B stride -> 2-way bank aliasing only, which is free).
    __shared__ float lds[4][64 * 20];

    const int t     = blockIdx.x * blockDim.x + threadIdx.x;
    const int lane  = threadIdx.x & 63;
    const int wslot = threadIdx.x >> 6;

    float c[9];
#pragma unroll
    for (int i = 0; i < 9; ++i) c[i] = cells[i];   // uniform -> scalar loads

    const bool active = t < n_quads;
    const int  e0     = 4 * t;
    const bool full   = active && (e0 + 3 < n_edges);
    const unsigned long long fm = __ballot(full);
    const bool wave_full = (fm == 0xFFFFFFFFFFFFFFFFull);

    float v[12];

    if (full) {
        // streaming, read-once -> nontemporal (keep the coord table cached)
        i32x4 ss = __builtin_nontemporal_load((const i32x4*)esrc + t);
        i32x4 dd = __builtin_nontemporal_load((const i32x4*)edst + t);
        const f32x4* shp = (const f32x4*)(shifts + 12 * (size_t)t);
        f32x4 h0 = __builtin_nontemporal_load(shp + 0);
        f32x4 h1 = __builtin_nontemporal_load(shp + 1);
        f32x4 h2 = __builtin_nontemporal_load(shp + 2);

        // issue all 8 gathers before any compute
        float4 s0 = packed[ss.x], s1 = packed[ss.y], s2 = packed[ss.z], s3 = packed[ss.w];
        float4 d0 = packed[dd.x], d1 = packed[dd.y], d2 = packed[dd.z], d3 = packed[dd.w];

        float di[4], sw[4], mk[4];
        edge_math(d0.x - s0.x, d0.y - s0.y, d0.z - s0.z, h0.x, h0.y, h0.z, c, v[0], v[1],  v[2],  di[0], sw[0], mk[0]);
        edge_math(d1.x - s1.x, d1.y - s1.y, d1.z - s1.z, h0.w, h1.x, h1.y, c, v[3], v[4],  v[5],  di[1], sw[1], mk[1]);
        edge_math(d2.x - s2.x, d2.y - s2.y, d2.z - s2.z, h1.z, h1.w, h2.x, c, v[6], v[7],  v[8],  di[2], sw[2], mk[2]);
        edge_math(d3.x - s3.x, d3.y - s3.y, d3.z - s3.z, h2.y, h2.z, h2.w, c, v[9], v[10], v[11], di[3], sw[3], mk[3]);

        // dist/sw/mask: lane-contiguous full lines -> nt.
        f32x4 od = { di[0], di[1], di[2], di[3] };
        f32x4 os = { sw[0], sw[1], sw[2], sw[3] };
        f32x4 om = { mk[0], mk[1], mk[2], mk[3] };
        __builtin_nontemporal_store(od, (f32x4*)out_dist + t);
        __builtin_nontemporal_store(os, (f32x4*)out_sw   + t);
        __builtin_nontemporal_store(om, (f32x4*)out_mask + t);

        if (wave_full) {
            // stage this thread's 12 vec floats into its padded LDS row
            float* row = &lds[wslot][lane * 20];
            f32x4 w0 = { v[0], v[1],  v[2],  v[3]  };
            f32x4 w1 = { v[4], v[5],  v[6],  v[7]  };
            f32x4 w2 = { v[8], v[9],  v[10], v[11] };
            *(f32x4*)(row + 0) = w0;
            *(f32x4*)(row + 4) = w1;
            *(f32x4*)(row + 8) = w2;
        }
    }

    __builtin_amdgcn_sched_barrier(0);   // keep ds_writes before ds_reads

    if (full && wave_full) {
        // wave-synchronous readback: 192 float4s of the wave's 768-float
        // region, lane-contiguous per instruction -> nt dwordx4 stores
        // (no L2 write-allocate churn, no striding amplification).
        const size_t w = (size_t)blockIdx.x * 4 + wslot;
        float* base = out_vec + w * 768;
#pragma unroll
        for (int k = 0; k < 3; ++k) {
            const int f   = k * 256 + 4 * lane;   // region float offset
            const int u   = f / 12;               // source row
            const int col = f % 12;               // {0,4,8}: never crosses row
            f32x4 val = *(const f32x4*)&lds[wslot][u * 20 + col];
            __builtin_nontemporal_store(val, (f32x4*)(base + f));
        }
    } else if (full) {
        // partial wave: R5-style cached strided stores (rare tail only)
        float4* ov = (float4*)(out_vec + 12 * (size_t)t);
        ov[0] = make_float4(v[0], v[1], v[2],  v[3]);
        ov[1] = make_float4(v[4], v[5], v[6],  v[7]);
        ov[2] = make_float4(v[8], v[9], v[10], v[11]);
    }

    if (active && !full) {
        for (int e = e0; e < n_edges; ++e) {
            float4 s = packed[esrc[e]], d = packed[edst[e]];
            float v0, v1, v2, di, sw, mk;
            edge_math(d.x - s.x, d.y - s.y, d.z - s.z,
                      shifts[3 * (size_t)e], shifts[3 * (size_t)e + 1],
                      shifts[3 * (size_t)e + 2], c, v0, v1, v2, di, sw, mk);
            out_vec[3 * (size_t)e]     = v0;
            out_vec[3 * (size_t)e + 1] = v1;
            out_vec[3 * (size_t)e + 2] = v2;
            out_dist[e] = di;
            out_sw[e]   = sw;
            out_mask[e] = mk;
        }
    }
}

// ---- fallback (ws too small): 12B struct gathers straight from coords ----
struct F3 { float x, y, z; };

__global__ __launch_bounds__(256) void GraphProcessor_fallback_kernel(
    const float* __restrict__ coords,
    const int*   __restrict__ esrc,
    const int*   __restrict__ edst,
    const float* __restrict__ shifts,
    const float* __restrict__ cells,
    float* __restrict__ out_vec,
    float* __restrict__ out_dist,
    float* __restrict__ out_sw,
    float* __restrict__ out_mask,
    int n_quads, int n_edges)
{
#pragma clang fp contract(off)
    int t = blockIdx.x * blockDim.x + threadIdx.x;
    if (t >= n_quads) return;

    float c[9];
#pragma unroll
    for (int i = 0; i < 9; ++i) c[i] = cells[i];

    const F3* nodes = (const F3*)coords;
    const int e0 = 4 * t;

    if (e0 + 3 < n_edges) {
        i32x4 ss = __builtin_nontemporal_load((const i32x4*)esrc + t);
        i32x4 dd = __builtin_nontemporal_load((const i32x4*)edst + t);
        const f32x4* shp = (const f32x4*)(shifts + 12 * (size_t)t);
        f32x4 h0 = __builtin_nontemporal_load(shp + 0);
        f32x4 h1 = __builtin_nontemporal_load(shp + 1);
        f32x4 h2 = __builtin_nontemporal_load(shp + 2);

        F3 s0 = nodes[ss.x], s1 = nodes[ss.y], s2 = nodes[ss.z], s3 = nodes[ss.w];
        F3 d0 = nodes[dd.x], d1 = nodes[dd.y], d2 = nodes[dd.z], d3 = nodes[dd.w];

        float v[12], di[4], sw[4], mk[4];
        edge_math(d0.x - s0.x, d0.y - s0.y, d0.z - s0.z, h0.x, h0.y, h0.z, c, v[0], v[1],  v[2],  di[0], sw[0], mk[0]);
        edge_math(d1.x - s1.x, d1.y - s1.y, d1.z - s1.z, h0.w, h1.x, h1.y, c, v[3], v[4],  v[5],  di[1], sw[1], mk[1]);
        edge_math(d2.x - s2.x, d2.y - s2.y, d2.z - s2.z, h1.z, h1.w, h2.x, c, v[6], v[7],  v[8],  di[2], sw[2], mk[2]);
        edge_math(d3.x - s3.x, d3.y - s3.y, d3.z - s3.z, h2.y, h2.z, h2.w, c, v[9], v[10], v[11], di[3], sw[3], mk[3]);

        float4* ov = (float4*)(out_vec + 12 * (size_t)t);
        ov[0] = make_float4(v[0], v[1], v[2],  v[3]);
        ov[1] = make_float4(v[4], v[5], v[6],  v[7]);
        ov[2] = make_float4(v[8], v[9], v[10], v[11]);

        f32x4 od = { di[0], di[1], di[2], di[3] };
        f32x4 os = { sw[0], sw[1], sw[2], sw[3] };
        f32x4 om = { mk[0], mk[1], mk[2], mk[3] };
        __builtin_nontemporal_store(od, (f32x4*)out_dist + t);
        __builtin_nontemporal_store(os, (f32x4*)out_sw   + t);
        __builtin_nontemporal_store(om, (f32x4*)out_mask + t);
    } else {
        for (int e = e0; e < n_edges; ++e) {
            F3 s = nodes[esrc[e]], d = nodes[edst[e]];
            float v0, v1, v2, di, sw, mk;
            edge_math(d.x - s.x, d.y - s.y, d.z - s.z,
                      shifts[3 * (size_t)e], shifts[3 * (size_t)e + 1],
                      shifts[3 * (size_t)e + 2], c, v0, v1, v2, di, sw, mk);
            out_vec[3 * (size_t)e]     = v0;
            out_vec[3 * (size_t)e + 1] = v1;
            out_vec[3 * (size_t)e + 2] = v2;
            out_dist[e] = di;
            out_sw[e]   = sw;
            out_mask[e] = mk;
        }
    }
}

extern "C" void kernel_launch(void* const* d_in, const int* in_sizes, int n_in,
                              void* d_out, int out_size, void* d_ws, size_t ws_size,
                              hipStream_t stream) {
    const float* coords = (const float*)d_in[0];
    const int*   esrc   = (const int*)d_in[1];
    const int*   edst   = (const int*)d_in[2];
    const float* shifts = (const float*)d_in[3];
    const float* cells  = (const float*)d_in[4];

    const int N = in_sizes[0] / 3;  // n_nodes
    const int E = in_sizes[1];      // n_edges

    float* out      = (float*)d_out;
    float* out_vec  = out;                     // [E,3]
    float* out_dist = out + 3 * (size_t)E;     // [E]
    float* out_sw   = out_dist + E;            // [E]
    float* out_mask = out_sw + E;              // [E]

    const int n_quads = (E + 3) / 4;
    dim3 block(256);
    dim3 grid((n_quads + 255) / 256);

    if (ws_size >= (size_t)N * sizeof(float4)) {
        float4* packed = (float4*)d_ws;
        pack_coords_kernel<<<(N + 255) / 256, 256, 0, stream>>>(coords, packed, N);
        GraphProcessor_64012192579962_kernel<<<grid, block, 0, stream>>>(
            packed, esrc, edst, shifts, cells,
            out_vec, out_dist, out_sw, out_mask, n_quads, E);
    } else {
        GraphProcessor_fallback_kernel<<<grid, block, 0, stream>>>(
            coords, esrc, edst, shifts, cells,
            out_vec, out_dist, out_sw, out_mask, n_quads, E);
    }
}

// Round 12
// 162.809 us; speedup vs baseline: 1.0891x; 1.0158x over previous
//
#include <hip/hip_runtime.h>

// All tensors float32. Output = concat(vec[3E], dist[E], switch[E], mask[E]).
//
// R2: packed float4[N] table in d_ws -> 1 dwordx4 gather/node. 65us.
// R5: nt streaming loads; cached strided vec stores; nt dist/sw/mask.
//   Bytes at ideal (47/75MB), dur flat 65us => not BW-bound.
// R6/R11 batching curve (8/4/2 edges per thread = 72/65/66us): dur invariant
//   to wave count AND per-wave MLP => fixed-rate resource.
// R12: LDS-transposed lane-contiguous nt vec stores: 65->59us, bytes
//   UNCHANGED => the win was REQUEST COUNT (strided wave-store ~170 L2
//   requests -> 48). Model: per-XCD L2 request-rate wall, ~8 req/cy/XCD.
//   Per 4-edge wave: 512 gather req (75%, irreducible: 2 random nodes/edge)
//   + ~80 stream-read + ~96 store req ~= 690 -> ~56us modeled ~= 59 measured.
// R13: isolate the LAST un-A/B'd policy knob - nt on streaming LOADS
//   (carried since R3, never isolated; suspected of blocking L3 allocation
//   of the 54MB input set => persistent 47MB/iter HBM FETCH). Change:
//   plain cached loads for esrc/edst/shifts. Everything else byte-identical
//   to R12. Predict: FETCH collapses to ~5-15MB if nt was blocking L3
//   retention (else ~47MB); dur 57-61 flat if request-bound (=> ROOFLINE
//   next round), 53-57 if HBM read service co-limited.
// R14: resubmit of R13 unchanged - R13 died in infra (GPU acquisition
//   timeout, pre-compile), no counters; the A/B has not run. Prediction
//   stands. Arithmetic unchanged (bit-exact: d<5 cliff; fp contract OFF,
//   numpy op order, OCML sqrtf).

typedef float f32x4 __attribute__((ext_vector_type(4)));
typedef int   i32x4 __attribute__((ext_vector_type(4)));

__device__ __forceinline__ void edge_math(
    float dx0, float dx1, float dx2,
    float sh0, float sh1, float sh2, const float c[9],
    float& v0, float& v1, float& v2, float& dist, float& sw, float& mk)
{
#pragma clang fp contract(off)
    float m0 = sh0 * c[0]; m0 = m0 + sh1 * c[3]; m0 = m0 + sh2 * c[6];
    float m1 = sh0 * c[1]; m1 = m1 + sh1 * c[4]; m1 = m1 + sh2 * c[7];
    float m2 = sh0 * c[2]; m2 = m2 + sh1 * c[5]; m2 = m2 + sh2 * c[8];
    v0 = dx0 + m0; v1 = dx1 + m1; v2 = dx2 + m2;
    float q = v0 * v0; q = q + v1 * v1; q = q + v2 * v2;
    dist = sqrtf(q);
    bool m = dist < 5.0f;
    float cv = cosf(dist * 0.62831853f);   // f32(pi/5)
    sw = m ? (0.5f * cv + 0.5f) : 0.0f;
    mk = m ? 1.0f : 0.0f;
}

// ---- prepass: coords[N,3] -> packed float4[N] in ws ----
// cached stores: the table is the one thing we WANT resident in L2/L3.
__global__ __launch_bounds__(256) void pack_coords_kernel(
    const float* __restrict__ coords, float4* __restrict__ packed, int n_nodes)
{
    int i = blockIdx.x * blockDim.x + threadIdx.x;
    if (i >= n_nodes) return;
    const float* p = coords + 3 * (size_t)i;
    packed[i] = make_float4(p[0], p[1], p[2], 0.0f);
}

// ---- main kernel: 4 edges/thread, cached streaming loads,
//      LDS-transposed lane-contiguous nt vec stores ----
__global__ __launch_bounds__(256) void GraphProcessor_64012192579962_kernel(
    const float4* __restrict__ packed,  // [N] xyz_
    const int*   __restrict__ esrc,     // [E]
    const int*   __restrict__ edst,     // [E]
    const float* __restrict__ shifts,   // [E,3]
    const float* __restrict__ cells,    // [9]
    float* __restrict__ out_vec,        // [E,3]
    float* __restrict__ out_dist,       // [E]
    float* __restrict__ out_sw,         // [E]
    float* __restrict__ out_mask,       // [E]
    int n_quads, int n_edges)
{
#pragma clang fp contract(off)
    // per-wave transpose buffer: 64 rows x 20 floats (pad 12->20: 16B-aligned
    // rows, 80B stride -> 2-way bank aliasing only, which is free).
    __shared__ float lds[4][64 * 20];

    const int t     = blockIdx.x * blockDim.x + threadIdx.x;
    const int lane  = threadIdx.x & 63;
    const int wslot = threadIdx.x >> 6;

    float c[9];
#pragma unroll
    for (int i = 0; i < 9; ++i) c[i] = cells[i];   // uniform -> scalar loads

    const bool active = t < n_quads;
    const int  e0     = 4 * t;
    const bool full   = active && (e0 + 3 < n_edges);
    const unsigned long long fm = __ballot(full);
    const bool wave_full = (fm == 0xFFFFFFFFFFFFFFFFull);

    float v[12];

    if (full) {
        // R13: streaming loads now CACHED (nt removed - isolation A/B).
        i32x4 ss = ((const i32x4*)esrc)[t];
        i32x4 dd = ((const i32x4*)edst)[t];
        const f32x4* shp = (const f32x4*)(shifts + 12 * (size_t)t);
        f32x4 h0 = shp[0];
        f32x4 h1 = shp[1];
        f32x4 h2 = shp[2];

        // issue all 8 gathers before any compute (cached: table L2-resident)
        float4 s0 = packed[ss.x], s1 = packed[ss.y], s2 = packed[ss.z], s3 = packed[ss.w];
        float4 d0 = packed[dd.x], d1 = packed[dd.y], d2 = packed[dd.z], d3 = packed[dd.w];

        float di[4], sw[4], mk[4];
        edge_math(d0.x - s0.x, d0.y - s0.y, d0.z - s0.z, h0.x, h0.y, h0.z, c, v[0], v[1],  v[2],  di[0], sw[0], mk[0]);
        edge_math(d1.x - s1.x, d1.y - s1.y, d1.z - s1.z, h0.w, h1.x, h1.y, c, v[3], v[4],  v[5],  di[1], sw[1], mk[1]);
        edge_math(d2.x - s2.x, d2.y - s2.y, d2.z - s2.z, h1.z, h1.w, h2.x, c, v[6], v[7],  v[8],  di[2], sw[2], mk[2]);
        edge_math(d3.x - s3.x, d3.y - s3.y, d3.z - s3.z, h2.y, h2.z, h2.w, c, v[9], v[10], v[11], di[3], sw[3], mk[3]);

        // dist/sw/mask: lane-contiguous full lines -> nt.
        f32x4 od = { di[0], di[1], di[2], di[3] };
        f32x4 os = { sw[0], sw[1], sw[2], sw[3] };
        f32x4 om = { mk[0], mk[1], mk[2], mk[3] };
        __builtin_nontemporal_store(od, (f32x4*)out_dist + t);
        __builtin_nontemporal_store(os, (f32x4*)out_sw   + t);
        __builtin_nontemporal_store(om, (f32x4*)out_mask + t);

        if (wave_full) {
            // stage this thread's 12 vec floats into its padded LDS row
            float* row = &lds[wslot][lane * 20];
            f32x4 w0 = { v[0], v[1],  v[2],  v[3]  };
            f32x4 w1 = { v[4], v[5],  v[6],  v[7]  };
            f32x4 w2 = { v[8], v[9],  v[10], v[11] };
            *(f32x4*)(row + 0) = w0;
            *(f32x4*)(row + 4) = w1;
            *(f32x4*)(row + 8) = w2;
        }
    }

    __builtin_amdgcn_sched_barrier(0);   // keep ds_writes before ds_reads

    if (full && wave_full) {
        // wave-synchronous readback: 192 float4s of the wave's 768-float
        // region, lane-contiguous per instruction -> nt dwordx4 stores
        // (16 L2 granule-requests per wave-instr instead of ~56 strided).
        const size_t w = (size_t)blockIdx.x * 4 + wslot;
        float* base = out_vec + w * 768;
#pragma unroll
        for (int k = 0; k < 3; ++k) {
            const int f   = k * 256 + 4 * lane;   // region float offset
            const int u   = f / 12;               // source row
            const int col = f % 12;               // {0,4,8}: never crosses row
            f32x4 val = *(const f32x4*)&lds[wslot][u * 20 + col];
            __builtin_nontemporal_store(val, (f32x4*)(base + f));
        }
    } else if (full) {
        // partial wave: cached strided stores (rare tail only)
        float4* ov = (float4*)(out_vec + 12 * (size_t)t);
        ov[0] = make_float4(v[0], v[1], v[2],  v[3]);
        ov[1] = make_float4(v[4], v[5], v[6],  v[7]);
        ov[2] = make_float4(v[8], v[9], v[10], v[11]);
    }

    if (active && !full) {
        for (int e = e0; e < n_edges; ++e) {
            float4 s = packed[esrc[e]], d = packed[edst[e]];
            float v0, v1, v2, di, sw, mk;
            edge_math(d.x - s.x, d.y - s.y, d.z - s.z,
                      shifts[3 * (size_t)e], shifts[3 * (size_t)e + 1],
                      shifts[3 * (size_t)e + 2], c, v0, v1, v2, di, sw, mk);
            out_vec[3 * (size_t)e]     = v0;
            out_vec[3 * (size_t)e + 1] = v1;
            out_vec[3 * (size_t)e + 2] = v2;
            out_dist[e] = di;
            out_sw[e]   = sw;
            out_mask[e] = mk;
        }
    }
}

// ---- fallback (ws too small): 12B struct gathers straight from coords ----
struct F3 { float x, y, z; };

__global__ __launch_bounds__(256) void GraphProcessor_fallback_kernel(
    const float* __restrict__ coords,
    const int*   __restrict__ esrc,
    const int*   __restrict__ edst,
    const float* __restrict__ shifts,
    const float* __restrict__ cells,
    float* __restrict__ out_vec,
    float* __restrict__ out_dist,
    float* __restrict__ out_sw,
    float* __restrict__ out_mask,
    int n_quads, int n_edges)
{
#pragma clang fp contract(off)
    int t = blockIdx.x * blockDim.x + threadIdx.x;
    if (t >= n_quads) return;

    float c[9];
#pragma unroll
    for (int i = 0; i < 9; ++i) c[i] = cells[i];

    const F3* nodes = (const F3*)coords;
    const int e0 = 4 * t;

    if (e0 + 3 < n_edges) {
        i32x4 ss = ((const i32x4*)esrc)[t];
        i32x4 dd = ((const i32x4*)edst)[t];
        const f32x4* shp = (const f32x4*)(shifts + 12 * (size_t)t);
        f32x4 h0 = shp[0];
        f32x4 h1 = shp[1];
        f32x4 h2 = shp[2];

        F3 s0 = nodes[ss.x], s1 = nodes[ss.y], s2 = nodes[ss.z], s3 = nodes[ss.w];
        F3 d0 = nodes[dd.x], d1 = nodes[dd.y], d2 = nodes[dd.z], d3 = nodes[dd.w];

        float v[12], di[4], sw[4], mk[4];
        edge_math(d0.x - s0.x, d0.y - s0.y, d0.z - s0.z, h0.x, h0.y, h0.z, c, v[0], v[1],  v[2],  di[0], sw[0], mk[0]);
        edge_math(d1.x - s1.x, d1.y - s1.y, d1.z - s1.z, h0.w, h1.x, h1.y, c, v[3], v[4],  v[5],  di[1], sw[1], mk[1]);
        edge_math(d2.x - s2.x, d2.y - s2.y, d2.z - s2.z, h1.z, h1.w, h2.x, c, v[6], v[7],  v[8],  di[2], sw[2], mk[2]);
        edge_math(d3.x - s3.x, d3.y - s3.y, d3.z - s3.z, h2.y, h2.z, h2.w, c, v[9], v[10], v[11], di[3], sw[3], mk[3]);

        float4* ov = (float4*)(out_vec + 12 * (size_t)t);
        ov[0] = make_float4(v[0], v[1], v[2],  v[3]);
        ov[1] = make_float4(v[4], v[5], v[6],  v[7]);
        ov[2] = make_float4(v[8], v[9], v[10], v[11]);

        f32x4 od = { di[0], di[1], di[2], di[3] };
        f32x4 os = { sw[0], sw[1], sw[2], sw[3] };
        f32x4 om = { mk[0], mk[1], mk[2], mk[3] };
        __builtin_nontemporal_store(od, (f32x4*)out_dist + t);
        __builtin_nontemporal_store(os, (f32x4*)out_sw   + t);
        __builtin_nontemporal_store(om, (f32x4*)out_mask + t);
    } else {
        for (int e = e0; e < n_edges; ++e) {
            F3 s = nodes[esrc[e]], d = nodes[edst[e]];
            float v0, v1, v2, di, sw, mk;
            edge_math(d.x - s.x, d.y - s.y, d.z - s.z,
                      shifts[3 * (size_t)e], shifts[3 * (size_t)e + 1],
                      shifts[3 * (size_t)e + 2], c, v0, v1, v2, di, sw, mk);
            out_vec[3 * (size_t)e]     = v0;
            out_vec[3 * (size_t)e + 1] = v1;
            out_vec[3 * (size_t)e + 2] = v2;
            out_dist[e] = di;
            out_sw[e]   = sw;
            out_mask[e] = mk;
        }
    }
}

extern "C" void kernel_launch(void* const* d_in, const int* in_sizes, int n_in,
                              void* d_out, int out_size, void* d_ws, size_t ws_size,
                              hipStream_t stream) {
    const float* coords = (const float*)d_in[0];
    const int*   esrc   = (const int*)d_in[1];
    const int*   edst   = (const int*)d_in[2];
    const float* shifts = (const float*)d_in[3];
    const float* cells  = (const float*)d_in[4];

    const int N = in_sizes[0] / 3;  // n_nodes
    const int E = in_sizes[1];      // n_edges

    float* out      = (float*)d_out;
    float* out_vec  = out;                     // [E,3]
    float* out_dist = out + 3 * (size_t)E;     // [E]
    float* out_sw   = out_dist + E;            // [E]
    float* out_mask = out_sw + E;              // [E]

    const int n_quads = (E + 3) / 4;
    dim3 block(256);
    dim3 grid((n_quads + 255) / 256);

    if (ws_size >= (size_t)N * sizeof(float4)) {
        float4* packed = (float4*)d_ws;
        pack_coords_kernel<<<(N + 255) / 256, 256, 0, stream>>>(coords, packed, N);
        GraphProcessor_64012192579962_kernel<<<grid, block, 0, stream>>>(
            packed, esrc, edst, shifts, cells,
            out_vec, out_dist, out_sw, out_mask, n_quads, E);
    } else {
        GraphProcessor_fallback_kernel<<<grid, block, 0, stream>>>(
            coords, esrc, edst, shifts, cells,
            out_vec, out_dist, out_sw, out_mask, n_quads, E);
    }
}